// Round 13
// baseline (557.095 us; speedup 1.0000x reference)
//
#include <hip/hip_runtime.h>

#define cN 16384
#define cE 65536
#define cT 2048
#define CAP 88

typedef __attribute__((ext_vector_type(8))) short short8;
typedef __attribute__((ext_vector_type(4))) float f32x4;
typedef __attribute__((ext_vector_type(4))) unsigned u32x4;

__device__ __forceinline__ short f2bf(float f){
  unsigned u = __float_as_uint(f);
  u = (u + 0x7FFFu + ((u >> 16) & 1u)) >> 16;
  return (short)u;
}
__device__ __forceinline__ float bf2f(short s){
  return __uint_as_float(((unsigned)(unsigned short)s) << 16);
}
__device__ __forceinline__ unsigned cvtpk(float lo, float hi){
  unsigned r;
  asm("v_cvt_pk_bf16_f32 %0, %1, %2" : "=v"(r) : "v"(lo), "v"(hi));
  return r;
}
__device__ __forceinline__ float sigm(float x){ return 1.f / (1.f + __expf(-x)); }
__device__ __forceinline__ float wred(float v){
  v += __shfl_xor(v, 32); v += __shfl_xor(v, 16); v += __shfl_xor(v, 8);
  v += __shfl_xor(v, 4);  v += __shfl_xor(v, 2);  v += __shfl_xor(v, 1);
  return v;
}
__device__ __forceinline__ float wredmax(float v){
  v = fmaxf(v, __shfl_xor(v, 32)); v = fmaxf(v, __shfl_xor(v, 16));
  v = fmaxf(v, __shfl_xor(v, 8));  v = fmaxf(v, __shfl_xor(v, 4));
  v = fmaxf(v, __shfl_xor(v, 2));  v = fmaxf(v, __shfl_xor(v, 1));
  return v;
}

// Fused setup: lin0 | h1p | w2f | b2f | wpack | deg, range-switched on blockIdx.
#define B_L0   4096
#define B_H1   20480
#define B_W2   22528
#define B_B2   22544
#define B_WP   22656
#define B_DEG  22912
__global__ __launch_bounds__(256) void k_setup(
    const float* __restrict__ x, const float* __restrict__ Wl0, const float* __restrict__ bl0,
    float* __restrict__ out,
    const float* __restrict__ ea, const float* __restrict__ We1, const float* __restrict__ be1,
    unsigned* __restrict__ h1p,
    const float* __restrict__ W2, short* __restrict__ w2f,
    const float* __restrict__ b2, short* __restrict__ b2f,
    const float* __restrict__ convW, const float* __restrict__ gWih,
    const float* __restrict__ gWhh, short* __restrict__ wpk,
    const int* __restrict__ ei, int* __restrict__ deg)
{
  int b = blockIdx.x, tid = threadIdx.x;
  if (b < B_L0){
    int i = b * 256 + tid;
    int n = i >> 6, f = i & 63;
    float acc = bl0[f] + x[n*3]*Wl0[f*3] + x[n*3+1]*Wl0[f*3+1] + x[n*3+2]*Wl0[f*3+2];
    out[i] = fmaxf(acc, 0.f);
  } else if (b < B_H1){
    int i = (b - B_L0) * 256 + tid;      // cE*64
    int e = i >> 6, k = i & 63;
    const float* a  = ea + e * 7;
    const float* w0 = We1 + k * 7;
    const float* w1 = We1 + (k + 64) * 7;
    float a0 = be1[k], a1 = be1[k + 64];
    #pragma unroll
    for (int c = 0; c < 7; c++){ float av = a[c]; a0 += av * w0[c]; a1 += av * w1[c]; }
    unsigned lo = (unsigned short)f2bf(fmaxf(a0, 0.f));
    unsigned hi = (unsigned short)f2bf(fmaxf(a1, 0.f));
    h1p[i] = lo | (hi << 16);
  } else if (b < B_W2){
    int o = (b - B_H1) * 256 + tid;
    int j = o & 7, l = (o >> 3) & 63, ks = (o >> 9) & 31, c = (o >> 14) & 7, fb = (o >> 17) & 3;
    int f = fb * 16 + (l & 15);
    int d = c * 8 + j;
    int k = ks * 4 + ((l >> 4) & 3);
    w2f[o] = f2bf(W2[(d * 64 + f) * 128 + k]);
  } else if (b < B_B2){
    int o = (b - B_W2) * 256 + tid;
    int j = o & 7, l = (o >> 3) & 63, ks2 = (o >> 9) & 1, fb = (o >> 10) & 3;
    int d = ks2 * 32 + ((l >> 4) & 3) * 8 + j;
    int f = fb * 16 + (l & 15);
    b2f[o] = f2bf(b2[d * 64 + f]);
  } else if (b < B_WP){
    int o = (b - B_B2) * 256 + tid;
    int j = o & 7, l = (o >> 3) & 63, kc = (o >> 9) & 1, cb = o >> 10;
    int k = kc * 32 + ((l >> 4) & 3) * 8 + j;
    int c16 = l & 15;
    float v;
    if (cb < 4)       v = convW[k * 64 + cb * 16 + c16];
    else if (cb < 16) v = gWih[((cb - 4) * 16 + c16) * 64 + k];
    else              v = gWhh[((cb - 16) * 16 + c16) * 64 + k];
    wpk[o] = f2bf(v);
  } else {
    int e = (b - B_WP) * 256 + tid;
    atomicAdd(&deg[ei[cE + e]], 1);
  }
}

// exclusive scan over 16384 degrees; fills cnt = max(deg,1) and cur = rowp copy.
__global__ __launch_bounds__(1024) void k_scan(const int* __restrict__ deg,
    int* __restrict__ rowp, int* __restrict__ cur, float* __restrict__ cnt)
{
  __shared__ int part[1024];
  int tid = threadIdx.x;
  int base = tid * 16;
  int loc[16]; int s = 0;
  #pragma unroll
  for (int i = 0; i < 16; i++){ loc[i] = s; s += deg[base + i]; }
  part[tid] = s;
  __syncthreads();
  for (int off = 1; off < 1024; off <<= 1){
    int v = (tid >= off) ? part[tid - off] : 0;
    __syncthreads();
    part[tid] += v;
    __syncthreads();
  }
  int inc = part[tid];
  int eb = inc - s;
  #pragma unroll
  for (int i = 0; i < 16; i++){
    int rv = eb + loc[i];
    rowp[base + i] = rv;
    cur[base + i] = rv;
    int dv = deg[base + i];
    cnt[base + i] = (float)(dv > 0 ? dv : 1);
  }
  if (tid == 1023) rowp[16384] = inc;
}

__global__ __launch_bounds__(256) void k_scatter(const int* __restrict__ ei,
    int* __restrict__ cur, int* __restrict__ esrc, int* __restrict__ eidx)
{
  int e = blockIdx.x * 256 + threadIdx.x;
  int t = ei[cE + e];
  int pos = atomicAdd(&cur[t], 1);
  esrc[pos] = ei[e];
  eidx[pos] = e;
}

// Fused bilinear aggregation + node update, producer/consumer wave specialization.
// Waves 0-3 build S (phase A); waves 4-7 contract with w2f (phase B) one chunk behind.
__global__ __launch_bounds__(512) void k_sagg(const float* __restrict__ outR,
    float* __restrict__ outW,
    const unsigned* __restrict__ h1p, const short* __restrict__ w2f,
    const short* __restrict__ b2f, const short* __restrict__ wpk,
    const float* __restrict__ convB, const float* __restrict__ bih,
    const float* __restrict__ bhh, const float* __restrict__ cnt,
    const int* __restrict__ rowp, const int* __restrict__ esrc,
    const int* __restrict__ eidx)
{
  __shared__ __align__(16) short S[2][16][1040];    // double-buffered, pos = k*8 + d
  __shared__ __align__(16) unsigned h1i[CAP][64];
  __shared__ __align__(16) float outsf[CAP][64];
  __shared__ __align__(16) short osb[16][72];
  __shared__ int ordb[32];
  int tid = threadIdx.x, w = tid >> 6, lane = tid & 63;
  bool prod = (w < 4);
  int pw = w & 3;                 // producer slot / consumer f-block
  int t0 = blockIdx.x * 16;

  int ebase = rowp[t0];
  int eend  = rowp[t0 + 16];
  int ecnt  = eend - ebase;
  bool fits = (ecnt <= CAP);
  int scnt  = fits ? ecnt : CAP;
  // ---- stage edge data once (all 8 waves) ----
  for (int i = w; i < scnt; i += 8){
    int eid = eidx[ebase + i];
    int src = esrc[ebase + i];
    h1i[i][lane] = h1p[(size_t)eid * 64 + lane];
    outsf[i][lane] = outR[(size_t)src * 64 + lane];
  }
  if (tid < 16) ordb[tid] = rowp[t0 + tid + 1] - rowp[t0 + tid];
  __syncthreads();
  if (tid < 16){
    int d = ordb[tid];
    int rank = 0;
    #pragma unroll
    for (int j = 0; j < 16; j++){
      int dj = ordb[j];
      rank += (dj > d) || (dj == d && j < tid);
    }
    ordb[16 + rank] = tid;
  }
  __syncthreads();

  int tsel[4], toff[4], tcnt[4];
  if (prod){
    #pragma unroll
    for (int g = 0; g < 4; g++){
      int pos = g * 4 + ((g & 1) ? (3 - pw) : pw);   // snake over sorted positions
      int ti = ordb[16 + pos];
      tsel[g] = ti;
      int t = t0 + ti;
      int a = rowp[t], b = rowp[t + 1];
      toff[g] = a - ebase; tcnt[g] = b - a;
    }
    // ---- os_t[d] once (lane = d), bf16 into osb ----
    #pragma unroll
    for (int g = 0; g < 4; g++){
      int ti = tsel[g];
      float os = 0.f;
      int tf = toff[g], tc = tcnt[g];
      for (int p = 0; p < tc; p++){
        int slot = tf + p;
        if (slot < CAP) os += outsf[slot][lane];
        else            os += outR[(size_t)esrc[ebase + slot] * 64 + lane];
      }
      osb[ti][lane] = (short)cvtpk(os, os);
    }
  }

  f32x4 acc[4] = {{0,0,0,0},{0,0,0,0},{0,0,0,0},{0,0,0,0}};
  int arow = lane & 15, kg = lane >> 4;
  short* tA  = (short*)&h1i[0][0];        // aliased after last h1i use (ph==7)
  short* mAp = tA + 16 * 72;

  for (int ph = 0; ph <= 8; ++ph){
    if (prod){
      if (ph < 8){
        int c = ph;
        int buf = c & 1;
        #pragma unroll
        for (int g = 0; g < 4; ++g){
          int ti = tsel[g];
          float a0[8], a1[8];
          #pragma unroll
          for (int d = 0; d < 8; d++){ a0[d] = 0.f; a1[d] = 0.f; }
          int tc = tcnt[g], tf = toff[g];
          if (fits){
            #pragma unroll 2
            for (int p = 0; p < tc; ++p){
              int slot = tf + p;
              unsigned u = h1i[slot][lane];
              float h1a = __uint_as_float(u << 16);
              float h1b = __uint_as_float(u & 0xFFFF0000u);
              f32x4 o0 = *(const f32x4*)&outsf[slot][c * 8];
              f32x4 o1 = *(const f32x4*)&outsf[slot][c * 8 + 4];
              a0[0] = fmaf(o0[0], h1a, a0[0]); a1[0] = fmaf(o0[0], h1b, a1[0]);
              a0[1] = fmaf(o0[1], h1a, a0[1]); a1[1] = fmaf(o0[1], h1b, a1[1]);
              a0[2] = fmaf(o0[2], h1a, a0[2]); a1[2] = fmaf(o0[2], h1b, a1[2]);
              a0[3] = fmaf(o0[3], h1a, a0[3]); a1[3] = fmaf(o0[3], h1b, a1[3]);
              a0[4] = fmaf(o1[0], h1a, a0[4]); a1[4] = fmaf(o1[0], h1b, a1[4]);
              a0[5] = fmaf(o1[1], h1a, a0[5]); a1[5] = fmaf(o1[1], h1b, a1[5]);
              a0[6] = fmaf(o1[2], h1a, a0[6]); a1[6] = fmaf(o1[2], h1b, a1[6]);
              a0[7] = fmaf(o1[3], h1a, a0[7]); a1[7] = fmaf(o1[3], h1b, a1[7]);
            }
          } else {
            for (int p = 0; p < tc; ++p){
              int slot = tf + p;
              if (slot < CAP){
                unsigned u = h1i[slot][lane];
                float h1a = __uint_as_float(u << 16);
                float h1b = __uint_as_float(u & 0xFFFF0000u);
                f32x4 o0 = *(const f32x4*)&outsf[slot][c * 8];
                f32x4 o1 = *(const f32x4*)&outsf[slot][c * 8 + 4];
                #pragma unroll
                for (int d = 0; d < 4; d++){
                  a0[d] = fmaf(o0[d], h1a, a0[d]); a1[d] = fmaf(o0[d], h1b, a1[d]);
                  a0[4+d] = fmaf(o1[d], h1a, a0[4+d]); a1[4+d] = fmaf(o1[d], h1b, a1[4+d]);
                }
              } else {
                int eid = eidx[ebase + slot];
                int src = esrc[ebase + slot];
                unsigned u = h1p[(size_t)eid * 64 + lane];
                float h1a = __uint_as_float(u << 16);
                float h1b = __uint_as_float(u & 0xFFFF0000u);
                #pragma unroll
                for (int d = 0; d < 8; d++){
                  float o = outR[(size_t)src * 64 + c * 8 + d];
                  a0[d] = fmaf(o, h1a, a0[d]); a1[d] = fmaf(o, h1b, a1[d]);
                }
              }
            }
          }
          u32x4 p0, p1;
          p0[0] = cvtpk(a0[0], a0[1]); p0[1] = cvtpk(a0[2], a0[3]);
          p0[2] = cvtpk(a0[4], a0[5]); p0[3] = cvtpk(a0[6], a0[7]);
          p1[0] = cvtpk(a1[0], a1[1]); p1[1] = cvtpk(a1[2], a1[3]);
          p1[2] = cvtpk(a1[4], a1[5]); p1[3] = cvtpk(a1[6], a1[7]);
          *(u32x4*)&S[buf][ti][lane * 8]       = p0;
          *(u32x4*)&S[buf][ti][512 + lane * 8] = p1;
        }
      } else {
        // ph == 8: stage target out rows (h1i is dead now)
        for (int i = tid; i < 512; i += 256){
          int r = i >> 5, c2 = (i & 31) * 2;
          float2 v = *(const float2*)&outR[(size_t)(t0 + r) * 64 + c2];
          *(unsigned*)&tA[r * 72 + c2] = cvtpk(v.x, v.y);
        }
      }
    } else if (ph > 0){
      int c = ph - 1;
      int buf = c & 1;
      const short* bbase = w2f + ((size_t)(pw * 8 + c) * 32) * 512 + lane * 8;
      #pragma unroll
      for (int ks8 = 0; ks8 < 8; ++ks8){
        #pragma unroll
        for (int j = 0; j < 4; ++j){
          int ks = ks8 * 4 + j;
          short8 afr = *(const short8*)&S[buf][arow][ks * 32 + kg * 8];
          short8 bfr = *(const short8*)(bbase + (size_t)ks * 512);
          acc[j] = __builtin_amdgcn_mfma_f32_16x16x32_bf16(afr, bfr, acc[j], 0, 0, 0);
        }
      }
    }
    __syncthreads();
  }

  // ================= consumer epilogue (bias + NNConv root + GRU) =================
  const short8* WF = (const short8*)wpk;
  int fcol = pw * 16 + arow;
  int trow = kg * 4;
  if (!prod){
    // bias term as 2 MFMA steps on chains 0/1
    #pragma unroll
    for (int ks2 = 0; ks2 < 2; ++ks2){
      short8 osf = *(const short8*)&osb[arow][ks2 * 32 + kg * 8];
      short8 bfr = *(const short8*)(b2f + ((size_t)((pw * 2 + ks2) * 64 + lane)) * 8);
      acc[ks2] = __builtin_amdgcn_mfma_f32_16x16x32_bf16(osf, bfr, acc[ks2], 0, 0, 0);
    }
    f32x4 accT;
    #pragma unroll
    for (int q = 0; q < 4; q++)
      accT[q] = (acc[0][q] + acc[1][q]) + (acc[2][q] + acc[3][q]);
    short8 aof0 = *(const short8*)&tA[arow * 72 + kg * 8];
    short8 aof1 = *(const short8*)&tA[arow * 72 + 32 + kg * 8];
    f32x4 cz = {0.f, 0.f, 0.f, 0.f};
    f32x4 cva0 = __builtin_amdgcn_mfma_f32_16x16x32_bf16(aof0, WF[(pw * 2 + 0) * 64 + lane], cz, 0, 0, 0);
    f32x4 cva1 = __builtin_amdgcn_mfma_f32_16x16x32_bf16(aof1, WF[(pw * 2 + 1) * 64 + lane], cz, 0, 0, 0);
    float cb_ = convB[fcol];
    #pragma unroll
    for (int q = 0; q < 4; q++){
      int node = t0 + trow + q;
      float icq = 1.0f / fmaxf(cnt[node], 1.0f);
      float m = fmaxf(accT[q] * icq + cva0[q] + cva1[q] + cb_, 0.f);
      mAp[(trow + q) * 72 + fcol] = f2bf(m);
    }
  }
  __syncthreads();
  if (!prod){
    short8 aof0 = *(const short8*)&tA[arow * 72 + kg * 8];
    short8 aof1 = *(const short8*)&tA[arow * 72 + 32 + kg * 8];
    short8 amf0 = *(const short8*)&mAp[arow * 72 + kg * 8];
    short8 amf1 = *(const short8*)&mAp[arow * 72 + 32 + kg * 8];
    f32x4 gir = {0,0,0,0}, giz = {0,0,0,0}, gin = {0,0,0,0};
    f32x4 ghr = {0,0,0,0}, ghz = {0,0,0,0}, ghn = {0,0,0,0};
    gir = __builtin_amdgcn_mfma_f32_16x16x32_bf16(amf0, WF[((4  + pw) * 2 + 0) * 64 + lane], gir, 0, 0, 0);
    gir = __builtin_amdgcn_mfma_f32_16x16x32_bf16(amf1, WF[((4  + pw) * 2 + 1) * 64 + lane], gir, 0, 0, 0);
    giz = __builtin_amdgcn_mfma_f32_16x16x32_bf16(amf0, WF[((8  + pw) * 2 + 0) * 64 + lane], giz, 0, 0, 0);
    giz = __builtin_amdgcn_mfma_f32_16x16x32_bf16(amf1, WF[((8  + pw) * 2 + 1) * 64 + lane], giz, 0, 0, 0);
    gin = __builtin_amdgcn_mfma_f32_16x16x32_bf16(amf0, WF[((12 + pw) * 2 + 0) * 64 + lane], gin, 0, 0, 0);
    gin = __builtin_amdgcn_mfma_f32_16x16x32_bf16(amf1, WF[((12 + pw) * 2 + 1) * 64 + lane], gin, 0, 0, 0);
    ghr = __builtin_amdgcn_mfma_f32_16x16x32_bf16(aof0, WF[((16 + pw) * 2 + 0) * 64 + lane], ghr, 0, 0, 0);
    ghr = __builtin_amdgcn_mfma_f32_16x16x32_bf16(aof1, WF[((16 + pw) * 2 + 1) * 64 + lane], ghr, 0, 0, 0);
    ghz = __builtin_amdgcn_mfma_f32_16x16x32_bf16(aof0, WF[((20 + pw) * 2 + 0) * 64 + lane], ghz, 0, 0, 0);
    ghz = __builtin_amdgcn_mfma_f32_16x16x32_bf16(aof1, WF[((20 + pw) * 2 + 1) * 64 + lane], ghz, 0, 0, 0);
    ghn = __builtin_amdgcn_mfma_f32_16x16x32_bf16(aof0, WF[((24 + pw) * 2 + 0) * 64 + lane], ghn, 0, 0, 0);
    ghn = __builtin_amdgcn_mfma_f32_16x16x32_bf16(aof1, WF[((24 + pw) * 2 + 1) * 64 + lane], ghn, 0, 0, 0);
    float bir = bih[fcol], biz = bih[64 + fcol], bin_ = bih[128 + fcol];
    float bhr = bhh[fcol], bhz = bhh[64 + fcol], bhn = bhh[128 + fcol];
    #pragma unroll
    for (int q = 0; q < 4; q++){
      size_t node = (size_t)(t0 + trow + q);
      float rr = sigm(gir[q] + bir + ghr[q] + bhr);
      float zz = sigm(giz[q] + biz + ghz[q] + bhz);
      float nn = tanhf(gin[q] + bin_ + rr * (ghn[q] + bhn));
      float o = outR[node * 64 + fcol];
      outW[node * 64 + fcol] = (1.f - zz) * nn + zz * o;
    }
  }
}

// Fused Set2Set step with in-kernel combine of the PREVIOUS step's partials.
// Page p = scal + p*256: [0..63]=hs, [64..127]=cs.  st==0 self-initializes.
__global__ __launch_bounds__(256) void k_dotsF(const float* __restrict__ out,
    const float* __restrict__ Wih, const float* __restrict__ Whh,
    const float* __restrict__ bih, const float* __restrict__ bhh,
    float* __restrict__ scal,
    const float* __restrict__ rbI, const float* __restrict__ bmI, const float* __restrict__ esI,
    float* __restrict__ rbO, float* __restrict__ bmO, float* __restrict__ esO, int st)
{
  __shared__ float q[128];
  __shared__ float hsL[64];
  __shared__ float gsh[4][64];
  __shared__ float hsh[64];
  __shared__ float smax[4];
  __shared__ float otile[64][64];
  __shared__ float sarr[64];
  __shared__ float ebuf[64];
  __shared__ float rpart[4][64];
  __shared__ float redA[4], redB[4];
  const float* pg = scal + st * 256;
  float* pn = scal + (st + 1) * 256;
  int tid = threadIdx.x, gg = tid >> 6, lane = tid & 63;
  // ---- combine previous step's flash partials -> rv ----
  if (st > 0){
    float bm = bmI[tid];
    float m = wredmax(bm);
    if (lane == 0) redA[gg] = m;
    __syncthreads();
    float gmax = fmaxf(fmaxf(redA[0], redA[1]), fmaxf(redA[2], redA[3]));
    float ep = wred(__expf(bm - gmax) * esI[tid]);
    if (lane == 0) redB[gg] = ep;
    float racc = 0.f;
    for (int i = 0; i < 64; i++){
      int b = gg * 64 + i;
      racc += __expf(bmI[b] - gmax) * rbI[b * 64 + lane];
    }
    rpart[gg][lane] = racc;
    __syncthreads();
    if (gg == 0){
      float esum = redB[0] + redB[1] + redB[2] + redB[3];
      float r = rpart[0][lane] + rpart[1][lane] + rpart[2][lane] + rpart[3][lane];
      q[64 + lane] = r / esum;
    }
  } else if (gg == 0) q[64 + lane] = 0.f;
  if (gg == 0){
    float hs = (st == 0) ? 0.f : pg[lane];
    q[lane] = hs; hsL[lane] = hs;
  }
  __syncthreads();
  // ---- LSTM (redundant per block) ----
  float2 fq = *(const float2*)&q[2 * lane];
  float hv0 = hsL[lane];
  #pragma unroll 4
  for (int o = 0; o < 64; o++){
    int row = gg * 64 + o;
    float2 wv = *(const float2*)&Wih[(size_t)row * 128 + 2 * lane];
    float s = wv.x * fq.x + wv.y * fq.y + Whh[(size_t)row * 64 + lane] * hv0;
    s = wred(s);
    if (lane == 0) gsh[gg][o] = s;
  }
  __syncthreads();
  if (gg == 0){
    float gi = gsh[0][lane] + bih[lane]       + bhh[lane];
    float gf = gsh[1][lane] + bih[64 + lane]  + bhh[64 + lane];
    float gv = gsh[2][lane] + bih[128 + lane] + bhh[128 + lane];
    float go = gsh[3][lane] + bih[192 + lane] + bhh[192 + lane];
    float cs = (st == 0) ? 0.f : pg[64 + lane];
    float cn = sigm(gf) * cs + sigm(gi) * tanhf(gv);
    float hn = sigm(go) * tanhf(cn);
    hsh[lane] = hn;
    if (blockIdx.x == 0){ pn[lane] = hn; pn[64 + lane] = cn; }
  }
  __syncthreads();
  // ---- dots + flash-local softmax partials ----
  int nbase = blockIdx.x * 64 + gg * 16;
  float hv = hsh[lane];
  float wmax = -3.4e38f;
  #pragma unroll 4
  for (int i = 0; i < 16; i++){
    float v = out[(size_t)(nbase + i) * 64 + lane];
    otile[gg * 16 + i][lane] = v;
    float p = wred(v * hv);
    if (lane == 0) sarr[gg * 16 + i] = p;
    wmax = fmaxf(wmax, p);
  }
  if (lane == 0) smax[gg] = wmax;
  __syncthreads();
  float bm = fmaxf(fmaxf(smax[0], smax[1]), fmaxf(smax[2], smax[3]));
  if (tid < 64) ebuf[tid] = __expf(sarr[tid] - bm);
  __syncthreads();
  float racc = 0.f;
  #pragma unroll 4
  for (int i = 0; i < 16; i++)
    racc += ebuf[gg * 16 + i] * otile[gg * 16 + i][lane];
  rpart[gg][lane] = racc;
  __syncthreads();
  if (gg == 0){
    float r = rpart[0][lane] + rpart[1][lane] + rpart[2][lane] + rpart[3][lane];
    rbO[blockIdx.x * 64 + lane] = r;
  } else if (gg == 1){
    float es = wred(ebuf[lane]);
    if (lane == 0) esO[blockIdx.x] = es;
  } else if (gg == 2 && lane == 0) bmO[blockIdx.x] = bm;
}

// Final combine + memory LSTM + value head (1 block).
__global__ __launch_bounds__(256) void k_smFin(
    const float* __restrict__ rbI, const float* __restrict__ bmI, const float* __restrict__ esI,
    const float* __restrict__ Wih, const float* __restrict__ Whh,
    const float* __restrict__ bih, const float* __restrict__ bhh,
    const float* __restrict__ hx, const float* __restrict__ cx,
    const float* __restrict__ W3, const float* __restrict__ b3,
    float* __restrict__ scal, float* __restrict__ dout)
{
  __shared__ float redA[4], redB[4];
  __shared__ float rpart[4][64];
  __shared__ float pool[128];
  __shared__ float hxs[64];
  __shared__ float gsh[4][64];
  __shared__ float lob[64];
  int tid = threadIdx.x, wid = tid >> 6, lane = tid & 63;
  float bm = bmI[tid];
  float m = wredmax(bm);
  if (lane == 0) redA[wid] = m;
  __syncthreads();
  float gmax = fmaxf(fmaxf(redA[0], redA[1]), fmaxf(redA[2], redA[3]));
  float ep = wred(__expf(bm - gmax) * esI[tid]);
  if (lane == 0) redB[wid] = ep;
  float racc = 0.f;
  for (int i = 0; i < 64; i++){
    int b = wid * 64 + i;
    racc += __expf(bmI[b] - gmax) * rbI[b * 64 + lane];
  }
  rpart[wid][lane] = racc;
  __syncthreads();
  if (wid == 0){
    float esum = redB[0] + redB[1] + redB[2] + redB[3];
    float r = rpart[0][lane] + rpart[1][lane] + rpart[2][lane] + rpart[3][lane];
    pool[lane] = scal[3 * 256 + lane];     // hs3
    pool[64 + lane] = r / esum;            // r3
    hxs[lane] = hx[lane];
  }
  __syncthreads();
  float2 fq = *(const float2*)&pool[2 * lane];
  float hv = hxs[lane];
  #pragma unroll 4
  for (int o = 0; o < 64; o++){
    int row = wid * 64 + o;
    float2 wv = *(const float2*)&Wih[(size_t)row * 128 + 2 * lane];
    float s = wv.x * fq.x + wv.y * fq.y + Whh[(size_t)row * 64 + lane] * hv;
    s = wred(s);
    if (lane == 0) gsh[wid][o] = s;
  }
  __syncthreads();
  if (wid == 0){
    float gi = gsh[0][lane] + bih[lane]       + bhh[lane];
    float gf = gsh[1][lane] + bih[64 + lane]  + bhh[64 + lane];
    float gv = gsh[2][lane] + bih[128 + lane] + bhh[128 + lane];
    float go = gsh[3][lane] + bih[192 + lane] + bhh[192 + lane];
    float cn = sigm(gf) * cx[lane] + sigm(gi) * tanhf(gv);
    float hn = sigm(go) * tanhf(cn);
    dout[12289 + lane] = hn;
    dout[12353 + lane] = cn;
    scal[1024 + lane] = hn;
    lob[lane] = hn;
  }
  __syncthreads();
  if (wid == 0){
    float a = pool[lane] * W3[lane] + pool[64 + lane] * W3[64 + lane]
            + lob[lane] * W3[128 + lane];
    a = wred(a);
    if (lane == 0) dout[12288] = a + b3[0];
  }
}

// torsion head. pf[t, j<256] = out[nr[j*32 + t/64], t%64]; pf[t, 256..319] = lstm_out[t>>5]
__global__ __launch_bounds__(256) void k_head(const float* __restrict__ out,
    const int* __restrict__ nr, const float* __restrict__ scal,
    const float* __restrict__ W1, const float* __restrict__ b1,
    const float* __restrict__ W2, const float* __restrict__ b2,
    float* __restrict__ dout)
{
  __shared__ float pf[4][320];
  __shared__ float hb[4][64];
  int tid = threadIdx.x, wid = tid >> 6, lane = tid & 63;
  int t = blockIdx.x * 4 + wid;
  float lo = scal[1024 + (t >> 5)];
  #pragma unroll
  for (int rep = 0; rep < 4; rep++){
    int j = rep * 64 + lane;
    int idx = nr[j * 32 + (t >> 6)];
    pf[wid][j] = out[idx * 64 + (t & 63)];
  }
  pf[wid][256 + lane] = lo;
  __syncthreads();
  float acc = b1[lane];
  const float* w = W1 + lane * 320;
  #pragma unroll 4
  for (int j = 0; j < 320; j++) acc += pf[wid][j] * w[j];
  hb[wid][lane] = fmaxf(acc, 0.f);
  __syncthreads();
  if (lane < 6){
    float a2 = b2[lane];
    const float* w2 = W2 + lane * 64;
    #pragma unroll 4
    for (int f = 0; f < 64; f++) a2 += hb[wid][f] * w2[f];
    dout[t * 6 + lane] = a2;
  }
}

extern "C" void kernel_launch(void* const* d_in, const int* in_sizes, int n_in,
                              void* d_out, int out_size, void* d_ws, size_t ws_size,
                              hipStream_t stream)
{
  const float* x         = (const float*)d_in[0];
  const float* edge_attr = (const float*)d_in[1];
  const int*   ei        = (const int*)d_in[2];
  const int*   nonring   = (const int*)d_in[3];
  const float* hx        = (const float*)d_in[4];
  const float* cx        = (const float*)d_in[5];
  const float* W_lin0 = (const float*)d_in[6];  const float* b_lin0 = (const float*)d_in[7];
  const float* W_e1   = (const float*)d_in[8];  const float* b_e1   = (const float*)d_in[9];
  const float* W_e2   = (const float*)d_in[10]; const float* b_e2   = (const float*)d_in[11];
  const float* convW  = (const float*)d_in[12]; const float* convB  = (const float*)d_in[13];
  const float* gWih   = (const float*)d_in[14]; const float* gWhh   = (const float*)d_in[15];
  const float* gbih   = (const float*)d_in[16]; const float* gbhh   = (const float*)d_in[17];
  const float* sWih   = (const float*)d_in[18]; const float* sWhh   = (const float*)d_in[19];
  const float* sbih   = (const float*)d_in[20]; const float* sbhh   = (const float*)d_in[21];
  const float* mWih   = (const float*)d_in[22]; const float* mWhh   = (const float*)d_in[23];
  const float* mbih   = (const float*)d_in[24]; const float* mbhh   = (const float*)d_in[25];
  const float* W_lin1 = (const float*)d_in[26]; const float* b_lin1 = (const float*)d_in[27];
  const float* W_lin2 = (const float*)d_in[28]; const float* b_lin2 = (const float*)d_in[29];
  const float* W_lin3 = (const float*)d_in[30]; const float* b_lin3 = (const float*)d_in[31];
  float* dout = (float*)d_out;

  char* w = (char*)d_ws;
  float* outb = (float*)w;  w += (size_t)cN * 64 * 4;
  float* outb2= (float*)w;  w += (size_t)cN * 64 * 4;
  unsigned* h1p = (unsigned*)w;  w += (size_t)cE * 64 * 4;
  short* w2f  = (short*)w;  w += (size_t)64 * 8192 * 2;
  short* b2f  = (short*)w;  w += 4096 * 2;
  short* wpk  = (short*)w;  w += 28672 * 2;
  float* cntb = (float*)w;  w += cN * 4;
  float* rbufA= (float*)w;  w += 256 * 64 * 4;
  float* rbufB= (float*)w;  w += 256 * 64 * 4;
  float* bmA  = (float*)w;  w += 256 * 4;
  float* bmB  = (float*)w;  w += 256 * 4;
  float* esA  = (float*)w;  w += 256 * 4;
  float* esB  = (float*)w;  w += 256 * 4;
  float* scal = (float*)w;  w += 1088 * 4;
  int* deg  = (int*)w;  w += cN * 4;
  int* cur  = (int*)w;  w += cN * 4;
  int* rowp = (int*)w;  w += (cN + 1) * 4 + 60;   // keep alignment
  int* esrc = (int*)w;  w += cE * 4;
  int* eidx = (int*)w;  w += cE * 4;

  hipMemsetAsync(deg, 0, cN * 4, stream);

  k_setup<<<B_DEG, 256, 0, stream>>>(x, W_lin0, b_lin0, outb,
      edge_attr, W_e1, b_e1, h1p, W_e2, w2f, b_e2, b2f,
      convW, gWih, gWhh, wpk, ei, deg);
  k_scan<<<1, 1024, 0, stream>>>(deg, rowp, cur, cntb);
  k_scatter<<<cE / 256, 256, 0, stream>>>(ei, cur, esrc, eidx);

  // ping-pong: outb -> outb2 -> outb -> outb2
  k_sagg<<<cN / 16, 512, 0, stream>>>(outb,  outb2, h1p, w2f, b2f, wpk, convB,
      gbih, gbhh, cntb, rowp, esrc, eidx);
  k_sagg<<<cN / 16, 512, 0, stream>>>(outb2, outb,  h1p, w2f, b2f, wpk, convB,
      gbih, gbhh, cntb, rowp, esrc, eidx);
  k_sagg<<<cN / 16, 512, 0, stream>>>(outb,  outb2, h1p, w2f, b2f, wpk, convB,
      gbih, gbhh, cntb, rowp, esrc, eidx);

  k_dotsF<<<cN / 64, 256, 0, stream>>>(outb2, sWih, sWhh, sbih, sbhh, scal,
      rbufA, bmA, esA, rbufA, bmA, esA, 0);
  k_dotsF<<<cN / 64, 256, 0, stream>>>(outb2, sWih, sWhh, sbih, sbhh, scal,
      rbufA, bmA, esA, rbufB, bmB, esB, 1);
  k_dotsF<<<cN / 64, 256, 0, stream>>>(outb2, sWih, sWhh, sbih, sbhh, scal,
      rbufB, bmB, esB, rbufA, bmA, esA, 2);
  k_smFin<<<1, 256, 0, stream>>>(rbufA, bmA, esA,
      mWih, mWhh, mbih, mbhh, hx, cx, W_lin3, b_lin3, scal, dout);

  k_head<<<cT / 4, 256, 0, stream>>>(outb2, nonring, scal, W_lin1, b_lin1, W_lin2, b_lin2, dout);
}

// Round 14
// 481.618 us; speedup vs baseline: 1.1567x; 1.1567x over previous
//
#include <hip/hip_runtime.h>

#define cN 16384
#define cE 65536
#define cT 2048
#define CAP 88

typedef __attribute__((ext_vector_type(8))) short short8;
typedef __attribute__((ext_vector_type(4))) float f32x4;
typedef __attribute__((ext_vector_type(4))) unsigned u32x4;

__device__ __forceinline__ short f2bf(float f){
  unsigned u = __float_as_uint(f);
  u = (u + 0x7FFFu + ((u >> 16) & 1u)) >> 16;
  return (short)u;
}
__device__ __forceinline__ float bf2f(short s){
  return __uint_as_float(((unsigned)(unsigned short)s) << 16);
}
__device__ __forceinline__ unsigned cvtpk(float lo, float hi){
  unsigned r;
  asm("v_cvt_pk_bf16_f32 %0, %1, %2" : "=v"(r) : "v"(lo), "v"(hi));
  return r;
}
__device__ __forceinline__ float sigm(float x){ return 1.f / (1.f + __expf(-x)); }
__device__ __forceinline__ float wred(float v){
  v += __shfl_xor(v, 32); v += __shfl_xor(v, 16); v += __shfl_xor(v, 8);
  v += __shfl_xor(v, 4);  v += __shfl_xor(v, 2);  v += __shfl_xor(v, 1);
  return v;
}
__device__ __forceinline__ float wredmax(float v){
  v = fmaxf(v, __shfl_xor(v, 32)); v = fmaxf(v, __shfl_xor(v, 16));
  v = fmaxf(v, __shfl_xor(v, 8));  v = fmaxf(v, __shfl_xor(v, 4));
  v = fmaxf(v, __shfl_xor(v, 2));  v = fmaxf(v, __shfl_xor(v, 1));
  return v;
}

// Fused setup: lin0 | h1p | w2f | b2f | wpack | deg, range-switched on blockIdx.
#define B_L0   4096
#define B_H1   20480
#define B_W2   22528
#define B_B2   22544
#define B_WP   22656
#define B_DEG  22912
__global__ __launch_bounds__(256) void k_setup(
    const float* __restrict__ x, const float* __restrict__ Wl0, const float* __restrict__ bl0,
    float* __restrict__ out,
    const float* __restrict__ ea, const float* __restrict__ We1, const float* __restrict__ be1,
    unsigned* __restrict__ h1p,
    const float* __restrict__ W2, short* __restrict__ w2f,
    const float* __restrict__ b2, short* __restrict__ b2f,
    const float* __restrict__ convW, const float* __restrict__ gWih,
    const float* __restrict__ gWhh, short* __restrict__ wpk,
    const int* __restrict__ ei, int* __restrict__ deg)
{
  int b = blockIdx.x, tid = threadIdx.x;
  if (b < B_L0){
    int i = b * 256 + tid;
    int n = i >> 6, f = i & 63;
    float acc = bl0[f] + x[n*3]*Wl0[f*3] + x[n*3+1]*Wl0[f*3+1] + x[n*3+2]*Wl0[f*3+2];
    out[i] = fmaxf(acc, 0.f);
  } else if (b < B_H1){
    int i = (b - B_L0) * 256 + tid;      // cE*64
    int e = i >> 6, k = i & 63;
    const float* a  = ea + e * 7;
    const float* w0 = We1 + k * 7;
    const float* w1 = We1 + (k + 64) * 7;
    float a0 = be1[k], a1 = be1[k + 64];
    #pragma unroll
    for (int c = 0; c < 7; c++){ float av = a[c]; a0 += av * w0[c]; a1 += av * w1[c]; }
    unsigned lo = (unsigned short)f2bf(fmaxf(a0, 0.f));
    unsigned hi = (unsigned short)f2bf(fmaxf(a1, 0.f));
    h1p[i] = lo | (hi << 16);
  } else if (b < B_W2){
    int o = (b - B_H1) * 256 + tid;
    int j = o & 7, l = (o >> 3) & 63, ks = (o >> 9) & 31, c = (o >> 14) & 7, fb = (o >> 17) & 3;
    int f = fb * 16 + (l & 15);
    int d = c * 8 + j;
    int k = ks * 4 + ((l >> 4) & 3);
    w2f[o] = f2bf(W2[(d * 64 + f) * 128 + k]);
  } else if (b < B_B2){
    int o = (b - B_W2) * 256 + tid;
    int j = o & 7, l = (o >> 3) & 63, ks2 = (o >> 9) & 1, fb = (o >> 10) & 3;
    int d = ks2 * 32 + ((l >> 4) & 3) * 8 + j;
    int f = fb * 16 + (l & 15);
    b2f[o] = f2bf(b2[d * 64 + f]);
  } else if (b < B_WP){
    int o = (b - B_B2) * 256 + tid;
    int j = o & 7, l = (o >> 3) & 63, kc = (o >> 9) & 1, cb = o >> 10;
    int k = kc * 32 + ((l >> 4) & 3) * 8 + j;
    int c16 = l & 15;
    float v;
    if (cb < 4)       v = convW[k * 64 + cb * 16 + c16];
    else if (cb < 16) v = gWih[((cb - 4) * 16 + c16) * 64 + k];
    else              v = gWhh[((cb - 16) * 16 + c16) * 64 + k];
    wpk[o] = f2bf(v);
  } else {
    int e = (b - B_WP) * 256 + tid;
    atomicAdd(&deg[ei[cE + e]], 1);
  }
}

// exclusive scan over 16384 degrees; fills cnt = max(deg,1) and cur = rowp copy.
__global__ __launch_bounds__(1024) void k_scan(const int* __restrict__ deg,
    int* __restrict__ rowp, int* __restrict__ cur, float* __restrict__ cnt)
{
  __shared__ int part[1024];
  int tid = threadIdx.x;
  int base = tid * 16;
  int loc[16]; int s = 0;
  #pragma unroll
  for (int i = 0; i < 16; i++){ loc[i] = s; s += deg[base + i]; }
  part[tid] = s;
  __syncthreads();
  for (int off = 1; off < 1024; off <<= 1){
    int v = (tid >= off) ? part[tid - off] : 0;
    __syncthreads();
    part[tid] += v;
    __syncthreads();
  }
  int inc = part[tid];
  int eb = inc - s;
  #pragma unroll
  for (int i = 0; i < 16; i++){
    int rv = eb + loc[i];
    rowp[base + i] = rv;
    cur[base + i] = rv;
    int dv = deg[base + i];
    cnt[base + i] = (float)(dv > 0 ? dv : 1);
  }
  if (tid == 1023) rowp[16384] = inc;
}

__global__ __launch_bounds__(256) void k_scatter(const int* __restrict__ ei,
    int* __restrict__ cur, int* __restrict__ esrc, int* __restrict__ eidx)
{
  int e = blockIdx.x * 256 + threadIdx.x;
  int t = ei[cE + e];
  int pos = atomicAdd(&cur[t], 1);
  esrc[pos] = ei[e];
  eidx[pos] = e;
}

// Fused bilinear aggregation + node update (NNConv root + GRU).
// Reads outR, writes outW (ping-pong). 4 independent MFMA acc chains.
__global__ __launch_bounds__(256) void k_sagg(const float* __restrict__ outR,
    float* __restrict__ outW,
    const unsigned* __restrict__ h1p, const short* __restrict__ w2f,
    const short* __restrict__ b2f, const short* __restrict__ wpk,
    const float* __restrict__ convB, const float* __restrict__ bih,
    const float* __restrict__ bhh, const float* __restrict__ cnt,
    const int* __restrict__ rowp, const int* __restrict__ esrc,
    const int* __restrict__ eidx)
{
  __shared__ __align__(16) short S[16][1040];       // chunk-local pos = k*8 + d
  __shared__ __align__(16) unsigned h1i[CAP][64];   // packed (h1[k=lane], h1[k=64+lane])
  __shared__ __align__(16) float outsf[CAP][64];
  __shared__ __align__(16) short osb[16][72];
  int tid = threadIdx.x, w = tid >> 6, lane = tid & 63;
  int t0 = blockIdx.x * 16;

  int ebase = rowp[t0];
  int eend  = rowp[t0 + 16];
  int ecnt  = eend - ebase;
  bool fits = (ecnt <= CAP);
  int scnt  = fits ? ecnt : CAP;
  // ---- stage edge data once (coalesced) ----
  for (int i = w; i < scnt; i += 4){
    int eid = eidx[ebase + i];
    int src = esrc[ebase + i];
    h1i[i][lane] = h1p[(size_t)eid * 64 + lane];
    outsf[i][lane] = outR[(size_t)src * 64 + lane];
  }
  int toff[4], tcnt[4];
  #pragma unroll
  for (int g = 0; g < 4; g++){
    int t = t0 + w * 4 + g;
    int a = rowp[t], b = rowp[t + 1];
    toff[g] = a - ebase; tcnt[g] = b - a;
  }
  __syncthreads();

  // ---- os_t[d] once (lane = d), bf16 into osb ----
  #pragma unroll
  for (int g = 0; g < 4; g++){
    int ti = w * 4 + g;
    float os = 0.f;
    int tf = toff[g], tc = tcnt[g];
    for (int p = 0; p < tc; p++){
      int slot = tf + p;
      if (slot < CAP) os += outsf[slot][lane];
      else            os += outR[(size_t)esrc[ebase + slot] * 64 + lane];
    }
    osb[ti][lane] = (short)cvtpk(os, os);
  }

  f32x4 acc[4] = {{0,0,0,0},{0,0,0,0},{0,0,0,0},{0,0,0,0}};
  int arow = lane & 15, kg = lane >> 4;
  for (int c = 0; c < 8; ++c){
    // ---- phase A: accumulate S-slice (d = c*8..c*8+7; k = lane / 64+lane) ----
    #pragma unroll
    for (int g = 0; g < 4; ++g){
      int ti = w * 4 + g;
      float a0[8], a1[8];
      #pragma unroll
      for (int d = 0; d < 8; d++){ a0[d] = 0.f; a1[d] = 0.f; }
      int tc = tcnt[g], tf = toff[g];
      if (fits){
        #pragma unroll 2
        for (int p = 0; p < tc; ++p){
          int slot = tf + p;
          unsigned u = h1i[slot][lane];
          float h1a = __uint_as_float(u << 16);
          float h1b = __uint_as_float(u & 0xFFFF0000u);
          f32x4 o0 = *(const f32x4*)&outsf[slot][c * 8];
          f32x4 o1 = *(const f32x4*)&outsf[slot][c * 8 + 4];
          a0[0] = fmaf(o0[0], h1a, a0[0]); a1[0] = fmaf(o0[0], h1b, a1[0]);
          a0[1] = fmaf(o0[1], h1a, a0[1]); a1[1] = fmaf(o0[1], h1b, a1[1]);
          a0[2] = fmaf(o0[2], h1a, a0[2]); a1[2] = fmaf(o0[2], h1b, a1[2]);
          a0[3] = fmaf(o0[3], h1a, a0[3]); a1[3] = fmaf(o0[3], h1b, a1[3]);
          a0[4] = fmaf(o1[0], h1a, a0[4]); a1[4] = fmaf(o1[0], h1b, a1[4]);
          a0[5] = fmaf(o1[1], h1a, a0[5]); a1[5] = fmaf(o1[1], h1b, a1[5]);
          a0[6] = fmaf(o1[2], h1a, a0[6]); a1[6] = fmaf(o1[2], h1b, a1[6]);
          a0[7] = fmaf(o1[3], h1a, a0[7]); a1[7] = fmaf(o1[3], h1b, a1[7]);
        }
      } else {
        for (int p = 0; p < tc; ++p){
          int slot = tf + p;
          if (slot < CAP){
            unsigned u = h1i[slot][lane];
            float h1a = __uint_as_float(u << 16);
            float h1b = __uint_as_float(u & 0xFFFF0000u);
            f32x4 o0 = *(const f32x4*)&outsf[slot][c * 8];
            f32x4 o1 = *(const f32x4*)&outsf[slot][c * 8 + 4];
            #pragma unroll
            for (int d = 0; d < 4; d++){
              a0[d] = fmaf(o0[d], h1a, a0[d]); a1[d] = fmaf(o0[d], h1b, a1[d]);
              a0[4+d] = fmaf(o1[d], h1a, a0[4+d]); a1[4+d] = fmaf(o1[d], h1b, a1[4+d]);
            }
          } else {
            int eid = eidx[ebase + slot];
            int src = esrc[ebase + slot];
            unsigned u = h1p[(size_t)eid * 64 + lane];
            float h1a = __uint_as_float(u << 16);
            float h1b = __uint_as_float(u & 0xFFFF0000u);
            #pragma unroll
            for (int d = 0; d < 8; d++){
              float o = outR[(size_t)src * 64 + c * 8 + d];
              a0[d] = fmaf(o, h1a, a0[d]); a1[d] = fmaf(o, h1b, a1[d]);
            }
          }
        }
      }
      u32x4 p0, p1;
      p0[0] = cvtpk(a0[0], a0[1]); p0[1] = cvtpk(a0[2], a0[3]);
      p0[2] = cvtpk(a0[4], a0[5]); p0[3] = cvtpk(a0[6], a0[7]);
      p1[0] = cvtpk(a1[0], a1[1]); p1[1] = cvtpk(a1[2], a1[3]);
      p1[2] = cvtpk(a1[4], a1[5]); p1[3] = cvtpk(a1[6], a1[7]);
      *(u32x4*)&S[ti][lane * 8]       = p0;
      *(u32x4*)&S[ti][512 + lane * 8] = p1;
    }
    __syncthreads();
    // ---- phase B: MFMA contraction, 4 independent acc chains ----
    const short* bbase = w2f + ((size_t)(w * 8 + c) * 32) * 512 + lane * 8;
    #pragma unroll
    for (int ks8 = 0; ks8 < 8; ++ks8){
      #pragma unroll
      for (int j = 0; j < 4; ++j){
        int ks = ks8 * 4 + j;
        short8 afr = *(const short8*)&S[arow][ks * 32 + kg * 8];
        short8 bfr = *(const short8*)(bbase + (size_t)ks * 512);
        acc[j] = __builtin_amdgcn_mfma_f32_16x16x32_bf16(afr, bfr, acc[j], 0, 0, 0);
      }
    }
    __syncthreads();
  }
  // ---- bias term as 2 MFMA steps on chains 0/1: acc += os @ B2 ----
  #pragma unroll
  for (int ks2 = 0; ks2 < 2; ++ks2){
    short8 osf = *(const short8*)&osb[arow][ks2 * 32 + kg * 8];
    short8 bfr = *(const short8*)(b2f + ((size_t)((w * 2 + ks2) * 64 + lane)) * 8);
    acc[ks2] = __builtin_amdgcn_mfma_f32_16x16x32_bf16(osf, bfr, acc[ks2], 0, 0, 0);
  }
  f32x4 accT;
  #pragma unroll
  for (int q = 0; q < 4; q++)
    accT[q] = (acc[0][q] + acc[1][q]) + (acc[2][q] + acc[3][q]);

  // ================= fused node update epilogue =================
  int fcol = w * 16 + arow;
  int trow = kg * 4;
  short* tA  = (short*)&h1i[0][0];        // [16][72] bf16 target out rows
  short* mAp = tA + 16 * 72;              // [16][72] bf16 m rows
  for (int i = tid; i < 512; i += 256){
    int r = i >> 5, c2 = (i & 31) * 2;
    float2 v = *(const float2*)&outR[(size_t)(t0 + r) * 64 + c2];
    *(unsigned*)&tA[r * 72 + c2] = cvtpk(v.x, v.y);
  }
  __syncthreads();
  const short8* WF = (const short8*)wpk;
  short8 aof0 = *(const short8*)&tA[arow * 72 + kg * 8];
  short8 aof1 = *(const short8*)&tA[arow * 72 + 32 + kg * 8];
  f32x4 cz = {0.f, 0.f, 0.f, 0.f};
  f32x4 cva0 = __builtin_amdgcn_mfma_f32_16x16x32_bf16(aof0, WF[(w * 2 + 0) * 64 + lane], cz, 0, 0, 0);
  f32x4 cva1 = __builtin_amdgcn_mfma_f32_16x16x32_bf16(aof1, WF[(w * 2 + 1) * 64 + lane], cz, 0, 0, 0);
  float cb_ = convB[fcol];
  #pragma unroll
  for (int q = 0; q < 4; q++){
    int node = t0 + trow + q;
    float icq = 1.0f / fmaxf(cnt[node], 1.0f);
    float m = fmaxf(accT[q] * icq + cva0[q] + cva1[q] + cb_, 0.f);
    mAp[(trow + q) * 72 + fcol] = f2bf(m);
  }
  __syncthreads();
  short8 amf0 = *(const short8*)&mAp[arow * 72 + kg * 8];
  short8 amf1 = *(const short8*)&mAp[arow * 72 + 32 + kg * 8];
  f32x4 gir = {0,0,0,0}, giz = {0,0,0,0}, gin = {0,0,0,0};
  f32x4 ghr = {0,0,0,0}, ghz = {0,0,0,0}, ghn = {0,0,0,0};
  gir = __builtin_amdgcn_mfma_f32_16x16x32_bf16(amf0, WF[((4  + w) * 2 + 0) * 64 + lane], gir, 0, 0, 0);
  gir = __builtin_amdgcn_mfma_f32_16x16x32_bf16(amf1, WF[((4  + w) * 2 + 1) * 64 + lane], gir, 0, 0, 0);
  giz = __builtin_amdgcn_mfma_f32_16x16x32_bf16(amf0, WF[((8  + w) * 2 + 0) * 64 + lane], giz, 0, 0, 0);
  giz = __builtin_amdgcn_mfma_f32_16x16x32_bf16(amf1, WF[((8  + w) * 2 + 1) * 64 + lane], giz, 0, 0, 0);
  gin = __builtin_amdgcn_mfma_f32_16x16x32_bf16(amf0, WF[((12 + w) * 2 + 0) * 64 + lane], gin, 0, 0, 0);
  gin = __builtin_amdgcn_mfma_f32_16x16x32_bf16(amf1, WF[((12 + w) * 2 + 1) * 64 + lane], gin, 0, 0, 0);
  ghr = __builtin_amdgcn_mfma_f32_16x16x32_bf16(aof0, WF[((16 + w) * 2 + 0) * 64 + lane], ghr, 0, 0, 0);
  ghr = __builtin_amdgcn_mfma_f32_16x16x32_bf16(aof1, WF[((16 + w) * 2 + 1) * 64 + lane], ghr, 0, 0, 0);
  ghz = __builtin_amdgcn_mfma_f32_16x16x32_bf16(aof0, WF[((20 + w) * 2 + 0) * 64 + lane], ghz, 0, 0, 0);
  ghz = __builtin_amdgcn_mfma_f32_16x16x32_bf16(aof1, WF[((20 + w) * 2 + 1) * 64 + lane], ghz, 0, 0, 0);
  ghn = __builtin_amdgcn_mfma_f32_16x16x32_bf16(aof0, WF[((24 + w) * 2 + 0) * 64 + lane], ghn, 0, 0, 0);
  ghn = __builtin_amdgcn_mfma_f32_16x16x32_bf16(aof1, WF[((24 + w) * 2 + 1) * 64 + lane], ghn, 0, 0, 0);
  float bir = bih[fcol], biz = bih[64 + fcol], bin_ = bih[128 + fcol];
  float bhr = bhh[fcol], bhz = bhh[64 + fcol], bhn = bhh[128 + fcol];
  #pragma unroll
  for (int q = 0; q < 4; q++){
    size_t node = (size_t)(t0 + trow + q);
    float rr = sigm(gir[q] + bir + ghr[q] + bhr);
    float zz = sigm(giz[q] + biz + ghz[q] + bhz);
    float nn = tanhf(gin[q] + bin_ + rr * (ghn[q] + bhn));
    float o = outR[node * 64 + fcol];
    outW[node * 64 + fcol] = (1.f - zz) * nn + zz * o;
  }
}

// Fused Set2Set step with in-kernel combine of the PREVIOUS step's partials.
// Page p = scal + p*256: [0..63]=hs, [64..127]=cs.  st==0 self-initializes.
__global__ __launch_bounds__(256) void k_dotsF(const float* __restrict__ out,
    const float* __restrict__ Wih, const float* __restrict__ Whh,
    const float* __restrict__ bih, const float* __restrict__ bhh,
    float* __restrict__ scal,
    const float* __restrict__ rbI, const float* __restrict__ bmI, const float* __restrict__ esI,
    float* __restrict__ rbO, float* __restrict__ bmO, float* __restrict__ esO, int st)
{
  __shared__ float q[128];
  __shared__ float hsL[64];
  __shared__ float gsh[4][64];
  __shared__ float hsh[64];
  __shared__ float smax[4];
  __shared__ float otile[64][64];
  __shared__ float sarr[64];
  __shared__ float ebuf[64];
  __shared__ float rpart[4][64];
  __shared__ float redA[4], redB[4];
  const float* pg = scal + st * 256;
  float* pn = scal + (st + 1) * 256;
  int tid = threadIdx.x, gg = tid >> 6, lane = tid & 63;
  // ---- combine previous step's flash partials -> rv ----
  if (st > 0){
    float bm = bmI[tid];
    float m = wredmax(bm);
    if (lane == 0) redA[gg] = m;
    __syncthreads();
    float gmax = fmaxf(fmaxf(redA[0], redA[1]), fmaxf(redA[2], redA[3]));
    float ep = wred(__expf(bm - gmax) * esI[tid]);
    if (lane == 0) redB[gg] = ep;
    float racc = 0.f;
    for (int i = 0; i < 64; i++){
      int b = gg * 64 + i;
      racc += __expf(bmI[b] - gmax) * rbI[b * 64 + lane];
    }
    rpart[gg][lane] = racc;
    __syncthreads();
    if (gg == 0){
      float esum = redB[0] + redB[1] + redB[2] + redB[3];
      float r = rpart[0][lane] + rpart[1][lane] + rpart[2][lane] + rpart[3][lane];
      q[64 + lane] = r / esum;
    }
  } else if (gg == 0) q[64 + lane] = 0.f;
  if (gg == 0){
    float hs = (st == 0) ? 0.f : pg[lane];
    q[lane] = hs; hsL[lane] = hs;
  }
  __syncthreads();
  // ---- LSTM (redundant per block) ----
  float2 fq = *(const float2*)&q[2 * lane];
  float hv0 = hsL[lane];
  #pragma unroll 4
  for (int o = 0; o < 64; o++){
    int row = gg * 64 + o;
    float2 wv = *(const float2*)&Wih[(size_t)row * 128 + 2 * lane];
    float s = wv.x * fq.x + wv.y * fq.y + Whh[(size_t)row * 64 + lane] * hv0;
    s = wred(s);
    if (lane == 0) gsh[gg][o] = s;
  }
  __syncthreads();
  if (gg == 0){
    float gi = gsh[0][lane] + bih[lane]       + bhh[lane];
    float gf = gsh[1][lane] + bih[64 + lane]  + bhh[64 + lane];
    float gv = gsh[2][lane] + bih[128 + lane] + bhh[128 + lane];
    float go = gsh[3][lane] + bih[192 + lane] + bhh[192 + lane];
    float cs = (st == 0) ? 0.f : pg[64 + lane];
    float cn = sigm(gf) * cs + sigm(gi) * tanhf(gv);
    float hn = sigm(go) * tanhf(cn);
    hsh[lane] = hn;
    if (blockIdx.x == 0){ pn[lane] = hn; pn[64 + lane] = cn; }
  }
  __syncthreads();
  // ---- dots + flash-local softmax partials ----
  int nbase = blockIdx.x * 64 + gg * 16;
  float hv = hsh[lane];
  float wmax = -3.4e38f;
  #pragma unroll 4
  for (int i = 0; i < 16; i++){
    float v = out[(size_t)(nbase + i) * 64 + lane];
    otile[gg * 16 + i][lane] = v;
    float p = wred(v * hv);
    if (lane == 0) sarr[gg * 16 + i] = p;
    wmax = fmaxf(wmax, p);
  }
  if (lane == 0) smax[gg] = wmax;
  __syncthreads();
  float bm = fmaxf(fmaxf(smax[0], smax[1]), fmaxf(smax[2], smax[3]));
  if (tid < 64) ebuf[tid] = __expf(sarr[tid] - bm);
  __syncthreads();
  float racc = 0.f;
  #pragma unroll 4
  for (int i = 0; i < 16; i++)
    racc += ebuf[gg * 16 + i] * otile[gg * 16 + i][lane];
  rpart[gg][lane] = racc;
  __syncthreads();
  if (gg == 0){
    float r = rpart[0][lane] + rpart[1][lane] + rpart[2][lane] + rpart[3][lane];
    rbO[blockIdx.x * 64 + lane] = r;
  } else if (gg == 1){
    float es = wred(ebuf[lane]);
    if (lane == 0) esO[blockIdx.x] = es;
  } else if (gg == 2 && lane == 0) bmO[blockIdx.x] = bm;
}

// Final combine + memory LSTM + value head (1 block).
__global__ __launch_bounds__(256) void k_smFin(
    const float* __restrict__ rbI, const float* __restrict__ bmI, const float* __restrict__ esI,
    const float* __restrict__ Wih, const float* __restrict__ Whh,
    const float* __restrict__ bih, const float* __restrict__ bhh,
    const float* __restrict__ hx, const float* __restrict__ cx,
    const float* __restrict__ W3, const float* __restrict__ b3,
    float* __restrict__ scal, float* __restrict__ dout)
{
  __shared__ float redA[4], redB[4];
  __shared__ float rpart[4][64];
  __shared__ float pool[128];
  __shared__ float hxs[64];
  __shared__ float gsh[4][64];
  __shared__ float lob[64];
  int tid = threadIdx.x, wid = tid >> 6, lane = tid & 63;
  float bm = bmI[tid];
  float m = wredmax(bm);
  if (lane == 0) redA[wid] = m;
  __syncthreads();
  float gmax = fmaxf(fmaxf(redA[0], redA[1]), fmaxf(redA[2], redA[3]));
  float ep = wred(__expf(bm - gmax) * esI[tid]);
  if (lane == 0) redB[wid] = ep;
  float racc = 0.f;
  for (int i = 0; i < 64; i++){
    int b = wid * 64 + i;
    racc += __expf(bmI[b] - gmax) * rbI[b * 64 + lane];
  }
  rpart[wid][lane] = racc;
  __syncthreads();
  if (wid == 0){
    float esum = redB[0] + redB[1] + redB[2] + redB[3];
    float r = rpart[0][lane] + rpart[1][lane] + rpart[2][lane] + rpart[3][lane];
    pool[lane] = scal[3 * 256 + lane];     // hs3
    pool[64 + lane] = r / esum;            // r3
    hxs[lane] = hx[lane];
  }
  __syncthreads();
  float2 fq = *(const float2*)&pool[2 * lane];
  float hv = hxs[lane];
  #pragma unroll 4
  for (int o = 0; o < 64; o++){
    int row = wid * 64 + o;
    float2 wv = *(const float2*)&Wih[(size_t)row * 128 + 2 * lane];
    float s = wv.x * fq.x + wv.y * fq.y + Whh[(size_t)row * 64 + lane] * hv;
    s = wred(s);
    if (lane == 0) gsh[wid][o] = s;
  }
  __syncthreads();
  if (wid == 0){
    float gi = gsh[0][lane] + bih[lane]       + bhh[lane];
    float gf = gsh[1][lane] + bih[64 + lane]  + bhh[64 + lane];
    float gv = gsh[2][lane] + bih[128 + lane] + bhh[128 + lane];
    float go = gsh[3][lane] + bih[192 + lane] + bhh[192 + lane];
    float cn = sigm(gf) * cx[lane] + sigm(gi) * tanhf(gv);
    float hn = sigm(go) * tanhf(cn);
    dout[12289 + lane] = hn;
    dout[12353 + lane] = cn;
    scal[1024 + lane] = hn;
    lob[lane] = hn;
  }
  __syncthreads();
  if (wid == 0){
    float a = pool[lane] * W3[lane] + pool[64 + lane] * W3[64 + lane]
            + lob[lane] * W3[128 + lane];
    a = wred(a);
    if (lane == 0) dout[12288] = a + b3[0];
  }
}

// torsion head. pf[t, j<256] = out[nr[j*32 + t/64], t%64]; pf[t, 256..319] = lstm_out[t>>5]
__global__ __launch_bounds__(256) void k_head(const float* __restrict__ out,
    const int* __restrict__ nr, const float* __restrict__ scal,
    const float* __restrict__ W1, const float* __restrict__ b1,
    const float* __restrict__ W2, const float* __restrict__ b2,
    float* __restrict__ dout)
{
  __shared__ float pf[4][320];
  __shared__ float hb[4][64];
  int tid = threadIdx.x, wid = tid >> 6, lane = tid & 63;
  int t = blockIdx.x * 4 + wid;
  float lo = scal[1024 + (t >> 5)];
  #pragma unroll
  for (int rep = 0; rep < 4; rep++){
    int j = rep * 64 + lane;
    int idx = nr[j * 32 + (t >> 6)];
    pf[wid][j] = out[idx * 64 + (t & 63)];
  }
  pf[wid][256 + lane] = lo;
  __syncthreads();
  float acc = b1[lane];
  const float* w = W1 + lane * 320;
  #pragma unroll 4
  for (int j = 0; j < 320; j++) acc += pf[wid][j] * w[j];
  hb[wid][lane] = fmaxf(acc, 0.f);
  __syncthreads();
  if (lane < 6){
    float a2 = b2[lane];
    const float* w2 = W2 + lane * 64;
    #pragma unroll 4
    for (int f = 0; f < 64; f++) a2 += hb[wid][f] * w2[f];
    dout[t * 6 + lane] = a2;
  }
}

extern "C" void kernel_launch(void* const* d_in, const int* in_sizes, int n_in,
                              void* d_out, int out_size, void* d_ws, size_t ws_size,
                              hipStream_t stream)
{
  const float* x         = (const float*)d_in[0];
  const float* edge_attr = (const float*)d_in[1];
  const int*   ei        = (const int*)d_in[2];
  const int*   nonring   = (const int*)d_in[3];
  const float* hx        = (const float*)d_in[4];
  const float* cx        = (const float*)d_in[5];
  const float* W_lin0 = (const float*)d_in[6];  const float* b_lin0 = (const float*)d_in[7];
  const float* W_e1   = (const float*)d_in[8];  const float* b_e1   = (const float*)d_in[9];
  const float* W_e2   = (const float*)d_in[10]; const float* b_e2   = (const float*)d_in[11];
  const float* convW  = (const float*)d_in[12]; const float* convB  = (const float*)d_in[13];
  const float* gWih   = (const float*)d_in[14]; const float* gWhh   = (const float*)d_in[15];
  const float* gbih   = (const float*)d_in[16]; const float* gbhh   = (const float*)d_in[17];
  const float* sWih   = (const float*)d_in[18]; const float* sWhh   = (const float*)d_in[19];
  const float* sbih   = (const float*)d_in[20]; const float* sbhh   = (const float*)d_in[21];
  const float* mWih   = (const float*)d_in[22]; const float* mWhh   = (const float*)d_in[23];
  const float* mbih   = (const float*)d_in[24]; const float* mbhh   = (const float*)d_in[25];
  const float* W_lin1 = (const float*)d_in[26]; const float* b_lin1 = (const float*)d_in[27];
  const float* W_lin2 = (const float*)d_in[28]; const float* b_lin2 = (const float*)d_in[29];
  const float* W_lin3 = (const float*)d_in[30]; const float* b_lin3 = (const float*)d_in[31];
  float* dout = (float*)d_out;

  char* w = (char*)d_ws;
  float* outb = (float*)w;  w += (size_t)cN * 64 * 4;
  float* outb2= (float*)w;  w += (size_t)cN * 64 * 4;
  unsigned* h1p = (unsigned*)w;  w += (size_t)cE * 64 * 4;
  short* w2f  = (short*)w;  w += (size_t)64 * 8192 * 2;
  short* b2f  = (short*)w;  w += 4096 * 2;
  short* wpk  = (short*)w;  w += 28672 * 2;
  float* cntb = (float*)w;  w += cN * 4;
  float* rbufA= (float*)w;  w += 256 * 64 * 4;
  float* rbufB= (float*)w;  w += 256 * 64 * 4;
  float* bmA  = (float*)w;  w += 256 * 4;
  float* bmB  = (float*)w;  w += 256 * 4;
  float* esA  = (float*)w;  w += 256 * 4;
  float* esB  = (float*)w;  w += 256 * 4;
  float* scal = (float*)w;  w += 1088 * 4;
  int* deg  = (int*)w;  w += cN * 4;
  int* cur  = (int*)w;  w += cN * 4;
  int* rowp = (int*)w;  w += (cN + 1) * 4 + 60;   // keep alignment
  int* esrc = (int*)w;  w += cE * 4;
  int* eidx = (int*)w;  w += cE * 4;

  hipMemsetAsync(deg, 0, cN * 4, stream);

  k_setup<<<B_DEG, 256, 0, stream>>>(x, W_lin0, b_lin0, outb,
      edge_attr, W_e1, b_e1, h1p, W_e2, w2f, b_e2, b2f,
      convW, gWih, gWhh, wpk, ei, deg);
  k_scan<<<1, 1024, 0, stream>>>(deg, rowp, cur, cntb);
  k_scatter<<<cE / 256, 256, 0, stream>>>(ei, cur, esrc, eidx);

  // ping-pong: outb -> outb2 -> outb -> outb2
  k_sagg<<<cN / 16, 256, 0, stream>>>(outb,  outb2, h1p, w2f, b2f, wpk, convB,
      gbih, gbhh, cntb, rowp, esrc, eidx);
  k_sagg<<<cN / 16, 256, 0, stream>>>(outb2, outb,  h1p, w2f, b2f, wpk, convB,
      gbih, gbhh, cntb, rowp, esrc, eidx);
  k_sagg<<<cN / 16, 256, 0, stream>>>(outb,  outb2, h1p, w2f, b2f, wpk, convB,
      gbih, gbhh, cntb, rowp, esrc, eidx);

  k_dotsF<<<cN / 64, 256, 0, stream>>>(outb2, sWih, sWhh, sbih, sbhh, scal,
      rbufA, bmA, esA, rbufA, bmA, esA, 0);
  k_dotsF<<<cN / 64, 256, 0, stream>>>(outb2, sWih, sWhh, sbih, sbhh, scal,
      rbufA, bmA, esA, rbufB, bmB, esB, 1);
  k_dotsF<<<cN / 64, 256, 0, stream>>>(outb2, sWih, sWhh, sbih, sbhh, scal,
      rbufB, bmB, esB, rbufA, bmA, esA, 2);
  k_smFin<<<1, 256, 0, stream>>>(rbufA, bmA, esA,
      mWih, mWhh, mbih, mbhh, hx, cx, W_lin3, b_lin3, scal, dout);

  k_head<<<cT / 4, 256, 0, stream>>>(outb2, nonring, scal, W_lin1, b_lin1, W_lin2, b_lin2, dout);
}